// Round 17
// baseline (164.423 us; speedup 1.0000x reference)
//
#include <hip/hip_runtime.h>
#include <math.h>

#define LN      2048
#define LOG2L   11
#define BB      16
#define HE      512            // H*E channels
#define KTOP    7              // int(log(2048)) = 7
#define TWO_PI  6.283185307179586f
#define RC      0.70710678118654752f

// XOR swizzle on element index for LDS FFT buffers.
#define SIG(e)  ((e) ^ (((e) >> 5) & 31))

struct c32 { float x, y; };
__device__ __forceinline__ c32 cmul(c32 a, c32 b) {
    return { a.x * b.x - a.y * b.y, a.x * b.y + a.y * b.x };
}
__device__ __forceinline__ c32 cadd(c32 a, c32 b) { return { a.x + b.x, a.y + b.y }; }
__device__ __forceinline__ c32 csub(c32 a, c32 b) { return { a.x - b.x, a.y - b.y }; }

// fp32 -> bf16 (RNE) and packed helpers for the staged z buffer.
__device__ __forceinline__ unsigned short f2bf(float f) {
    unsigned u = __float_as_uint(f);
    u = (u + 0x7FFFu + ((u >> 16) & 1u)) >> 16;
    return (unsigned short)u;
}
__device__ __forceinline__ unsigned pkz(float re, float im) {
    return (unsigned)f2bf(re) | ((unsigned)f2bf(im) << 16);
}

__device__ __forceinline__ void dft4(c32 a, c32 b, c32 c, c32 d,
                                     c32& y0, c32& y1, c32& y2, c32& y3) {
    c32 t0 = cadd(a, c), t1 = csub(a, c);
    c32 t2 = cadd(b, d);
    c32 t3 = { b.y - d.y, d.x - b.x };          // -i*(b-d)
    y0 = cadd(t0, t2);
    y1 = cadd(t1, t3);
    y2 = csub(t0, t2);
    y3 = csub(t1, t3);
}

__device__ __forceinline__ void dft8(const c32* x, c32* y) {
    c32 e0, e1, e2, e3, o0, o1, o2, o3;
    dft4(x[0], x[2], x[4], x[6], e0, e1, e2, e3);
    dft4(x[1], x[3], x[5], x[7], o0, o1, o2, o3);
    c32 p1 = { RC * (o1.x + o1.y), RC * (o1.y - o1.x) };
    c32 p2 = { o2.y, -o2.x };
    c32 p3 = { RC * (o3.y - o3.x), -RC * (o3.x + o3.y) };
    y[0] = cadd(e0, o0); y[4] = csub(e0, o0);
    y[1] = cadd(e1, p1); y[5] = csub(e1, p1);
    y[2] = cadd(e2, p2); y[6] = csub(e2, p2);
    y[3] = cadd(e3, p3); y[7] = csub(e3, p3);
}

// Twiddle set for one stage: W[k-1] = W^{pm*k}, k=1..7 (tree, depth<=2).
__device__ __forceinline__ void mk_tw_n(float invn, int pm, c32* W) {
    float sn, cs;
    __sincosf(-TWO_PI * invn * (float)pm, &sn, &cs);
    const c32 w1 = { cs, sn };
    const c32 w2 = cmul(w1, w1);
    const c32 w3 = cmul(w1, w2);
    const c32 w4 = cmul(w2, w2);
    W[0] = w1; W[1] = w2; W[2] = w3; W[3] = w4;
    W[4] = cmul(w1, w4); W[5] = cmul(w2, w4); W[6] = cmul(w3, w4);
}
__device__ __forceinline__ void mk_tw(int pm, c32* W) {
    mk_tw_n(1.0f / (float)LN, pm, W);
}

// Wave-local Stockham DIF radix-8 stage over a 512-pt row slice.
// 64 lanes x 1 butterfly. NO workgroup barrier: all LDS deps are intra-wave
// (in-order DS pipe); wave_barrier pins compiler order. [verified round 8]
template<int LOG2M, bool TW>
__device__ __forceinline__ void wave_r8(float2* Z, int rowbase, int lane) {
    c32 v[8];
    #pragma unroll
    for (int r = 0; r < 8; ++r) {
        float2 z = Z[SIG(rowbase + lane + (r << 6))];
        v[r] = { z.x, z.y };
    }
    c32 y[8];
    dft8(v, y);
    if (TW) {
        c32 W[7];
        mk_tw_n(1.0f / 512.f, lane & ~((1 << LOG2M) - 1), W);
        #pragma unroll
        for (int kk = 1; kk < 8; ++kk) y[kk] = cmul(y[kk], W[kk - 1]);
    }
    __builtin_amdgcn_wave_barrier();
    const int q_ = lane & ((1 << LOG2M) - 1);
    const int ob = q_ + ((lane - q_) << 3);      // q + 8*m*p
    #pragma unroll
    for (int kk = 0; kk < 8; ++kk)
        Z[SIG(rowbase + ob + (kk << LOG2M))] = make_float2(y[kk].x, y[kk].y);
    __builtin_amdgcn_wave_barrier();
}

// ---------------------------------------------------------------------------
// Kernel T v4: coalesced transpose, float4 global loads, writes PACKED
// z = (bf16(q), bf16(k)) as one uint per complex into [b][c][l] (64 MB, ws).
// ---------------------------------------------------------------------------
__global__ __launch_bounds__(256) void transpose_pack_kernel(
    const float* __restrict__ q, const float* __restrict__ k,
    unsigned* __restrict__ z) {
    __shared__ float2 tile[64][65];
    const int tid = threadIdx.x;
    const int bid = blockIdx.x;
    const int b  = bid >> 8;
    const int lt = (bid >> 3) & 31;
    const int ct = bid & 7;
    const int l0 = lt << 6, c0 = ct << 6;
    const int g16 = tid >> 4;               // 0..15
    const int m16 = (tid & 15) << 2;        // 0,4,..,60
    #pragma unroll
    for (int ii = 0; ii < 4; ++ii) {
        const int r = g16 + (ii << 4);      // l offset 0..63
        const size_t src = ((size_t)(b * LN + l0 + r)) * HE + c0 + m16;
        const float4 qv = *(const float4*)(q + src);
        const float4 kv = *(const float4*)(k + src);
        tile[r][m16 + 0] = make_float2(qv.x, kv.x);
        tile[r][m16 + 1] = make_float2(qv.y, kv.y);
        tile[r][m16 + 2] = make_float2(qv.z, kv.z);
        tile[r][m16 + 3] = make_float2(qv.w, kv.w);
    }
    __syncthreads();
    #pragma unroll
    for (int ii = 0; ii < 4; ++ii) {
        const int rc = g16 + (ii << 4);     // c offset 0..63
        const float2 t0 = tile[m16 + 0][rc];
        const float2 t1 = tile[m16 + 1][rc];
        const float2 t2 = tile[m16 + 2][rc];
        const float2 t3 = tile[m16 + 3][rc];
        unsigned* dst = z + ((size_t)(b * HE + c0 + rc)) * LN + l0 + m16;
        uint4 w;
        w.x = pkz(t0.x, t0.y);
        w.y = pkz(t1.x, t1.y);
        w.z = pkz(t2.x, t2.y);
        w.w = pkz(t3.x, t3.y);
        *(uint4*)dst = w;
    }
}

// ---------------------------------------------------------------------------
// Kernel A: four-step FFT (verified structure from round 8, now with bf16
// z input + no forced launch bounds). 2048 = 4(rows, reg-DFT4) x 512(wave-
// local radix-8^3). 3 __syncthreads/channel. Hermitian-half flush.
// x[512*n1+n2]; A[r][n2]=DFT4_n1; C=A*W2048^(n2 r); row r DFT512 -> X[4k2+r].
// ---------------------------------------------------------------------------
__global__ __launch_bounds__(256) void fft_4step_kernel(
    const unsigned* __restrict__ z,
    float* __restrict__ spec /* [BB][LN][2], only f<=1024 written */) {
    __shared__ float2 Z[LN];                     // 16 KB
    const int tid  = threadIdx.x;
    const int lane = tid & 63;
    const int w    = tid >> 6;
    const int rowbase = w << 9;
    const int wg   = blockIdx.x;                 // 2048
    const int b    = wg >> 7;                    // L2-locality mapping
    const int c0   = (wg & 127) << 2;
    const int n2   = tid << 1;                   // this thread's two columns

    float accx[4], accy[4];
    #pragma unroll
    for (int i = 0; i < 4; ++i) { accx[i] = 0.f; accy[i] = 0.f; }
    float a1024 = 0.f;

    // W_2048^1
    const c32 W1C = { 0.99999529380957617f, -0.00306795676296598f };

    #pragma unroll 1
    for (int ch = 0; ch < 4; ++ch) {
        const unsigned* zc = z + (((size_t)(b * HE + c0 + ch)) << LOG2L);
        // load columns n2, n2+1 for n1=0..3: one uint2 (8B) per n1, coalesced
        c32 za[4], zb[4];
        #pragma unroll
        for (int n1 = 0; n1 < 4; ++n1) {
            const uint2 u = *(const uint2*)(zc + (n1 << 9) + n2);
            za[n1].x = __uint_as_float(u.x << 16);
            za[n1].y = __uint_as_float(u.x & 0xFFFF0000u);
            zb[n1].x = __uint_as_float(u.y << 16);
            zb[n1].y = __uint_as_float(u.y & 0xFFFF0000u);
        }
        c32 ya0, ya1, ya2, ya3, yb0, yb1, yb2, yb3;
        dft4(za[0], za[1], za[2], za[3], ya0, ya1, ya2, ya3);
        dft4(zb[0], zb[1], zb[2], zb[3], yb0, yb1, yb2, yb3);
        // twiddle C[r][n2] = A[r][n2] * W_2048^{n2*r}
        float sn, cs;
        __sincosf(-(TWO_PI / (float)LN) * (float)n2, &sn, &cs);
        const c32 wa  = { cs, sn };
        const c32 wb  = cmul(wa, W1C);
        const c32 wa2 = cmul(wa, wa);
        const c32 wb2 = cmul(wb, wb);
        const c32 wa3 = cmul(wa2, wa);
        const c32 wb3 = cmul(wb2, wb);
        ya1 = cmul(ya1, wa);  yb1 = cmul(yb1, wb);
        ya2 = cmul(ya2, wa2); yb2 = cmul(yb2, wb2);
        ya3 = cmul(ya3, wa3); yb3 = cmul(yb3, wb3);

        __syncthreads();                         // Z free (prev unpack done)
        Z[SIG(n2)]            = make_float2(ya0.x, ya0.y);
        Z[SIG(n2 + 1)]        = make_float2(yb0.x, yb0.y);
        Z[SIG(512 + n2)]      = make_float2(ya1.x, ya1.y);
        Z[SIG(512 + n2 + 1)]  = make_float2(yb1.x, yb1.y);
        Z[SIG(1024 + n2)]     = make_float2(ya2.x, ya2.y);
        Z[SIG(1024 + n2 + 1)] = make_float2(yb2.x, yb2.y);
        Z[SIG(1536 + n2)]     = make_float2(ya3.x, ya3.y);
        Z[SIG(1536 + n2 + 1)] = make_float2(yb3.x, yb3.y);
        __syncthreads();

        // wave-local DFT-512 on row w (barrier-free stages)
        wave_r8<0, true >(Z, rowbase, lane);
        wave_r8<3, true >(Z, rowbase, lane);
        wave_r8<6, false>(Z, rowbase, lane);
        __syncthreads();

        // Hermitian-half unpack: S = Q*conj(K), f in [0,1024);
        // X[f=4k2+r] lives at e = 512r + k2
        #pragma unroll
        for (int i = 0; i < 4; ++i) {
            const int f  = tid + (i << 8);
            const int g  = (LN - f) & (LN - 1);
            const int e1 = ((f & 3) << 9) + (f >> 2);
            const int e2 = ((g & 3) << 9) + (g >> 2);
            const float2 zf = Z[SIG(e1)];
            const float2 zm = Z[SIG(e2)];
            const float Qr = 0.5f * (zf.x + zm.x);
            const float Qi = 0.5f * (zf.y - zm.y);
            const float Kr = 0.5f * (zf.y + zm.y);
            const float Ki = -0.5f * (zf.x - zm.x);
            accx[i] += Qr * Kr + Qi * Ki;
            accy[i] += Qi * Kr - Qr * Ki;
        }
        if (tid == 0) {                          // f = 1024 -> e = 256, S real
            const float2 zf = Z[SIG(256)];
            a1024 += zf.x * zf.y;
        }
    }
    #pragma unroll
    for (int i = 0; i < 4; ++i) {
        const int f = tid + (i << 8);
        atomicAdd(&spec[((size_t)b * LN + f) * 2 + 0], accx[i]);
        atomicAdd(&spec[((size_t)b * LN + f) * 2 + 1], accy[i]);
    }
    if (tid == 0)
        atomicAdd(&spec[((size_t)b * LN + 1024) * 2 + 0], a1024);
}

// ---------------------------------------------------------------------------
// Fallback (raw fp32 layout, round-3 path; flush gated to f<=1024) — only if
// ws is too small for the packed staging buffer.
// ---------------------------------------------------------------------------
template<int LOG2M>
__device__ __forceinline__ void r8_stage(float2* Z, int lane) {
    c32 v[32];
    #pragma unroll
    for (int u = 0; u < 4; ++u) {
        const int j = lane + (u << 6);
        #pragma unroll
        for (int r = 0; r < 8; ++r) {
            float2 z = Z[SIG(j + (r << 8))];
            v[(u << 3) + r] = { z.x, z.y };
        }
    }
    c32 y[32];
    #pragma unroll
    for (int u = 0; u < 4; ++u) {
        const int j  = lane + (u << 6);
        const int pm = j & ~((1 << LOG2M) - 1);
        dft8(&v[u << 3], &y[u << 3]);
        float sn, cs;
        __sincosf(-(TWO_PI / (float)LN) * (float)pm, &sn, &cs);
        c32 base = { cs, sn };
        c32 t = base;
        #pragma unroll
        for (int kk = 1; kk < 8; ++kk) {
            y[(u << 3) + kk] = cmul(y[(u << 3) + kk], t);
            if (kk < 7) t = cmul(t, base);
        }
    }
    __syncthreads();
    #pragma unroll
    for (int u = 0; u < 4; ++u) {
        const int j  = lane + (u << 6);
        const int q_ = j & ((1 << LOG2M) - 1);
        const int ob = q_ + ((j - q_) << 3);
        #pragma unroll
        for (int kk = 0; kk < 8; ++kk) {
            c32 yy = y[(u << 3) + kk];
            Z[SIG(ob + (kk << LOG2M))] = make_float2(yy.x, yy.y);
        }
    }
    __syncthreads();
}

__device__ __forceinline__ void r4_final(float2* Z, int lane) {
    c32 v[32];
    #pragma unroll
    for (int u = 0; u < 8; ++u) {
        const int j = lane + (u << 6);
        #pragma unroll
        for (int r = 0; r < 4; ++r) {
            float2 z = Z[SIG(j + (r << 9))];
            v[(u << 2) + r] = { z.x, z.y };
        }
    }
    __syncthreads();
    #pragma unroll
    for (int u = 0; u < 8; ++u) {
        const int j = lane + (u << 6);
        c32 y0, y1, y2, y3;
        dft4(v[u << 2], v[(u << 2) + 1], v[(u << 2) + 2], v[(u << 2) + 3],
             y0, y1, y2, y3);
        Z[SIG(j)]        = make_float2(y0.x, y0.y);
        Z[SIG(j + 512)]  = make_float2(y1.x, y1.y);
        Z[SIG(j + 1024)] = make_float2(y2.x, y2.y);
        Z[SIG(j + 1536)] = make_float2(y3.x, y3.y);
    }
    __syncthreads();
}

__global__ __launch_bounds__(256) void fft_fused_kernel(
    const float* __restrict__ qg, const float* __restrict__ kg,
    float* __restrict__ spec) {
    __shared__ float2 zb[4][LN];
    const int t    = threadIdx.x;
    const int bid  = blockIdx.x;
    const int wgid = ((bid & 7) << 8) | (bid >> 3);
    const int b    = wgid >> 7;
    const int c0   = (wgid & 127) << 2;
    #pragma unroll
    for (int i = 0; i < 8; ++i) {
        const int l = t + (i << 8);
        const size_t base = (size_t)(b * LN + l) * HE + c0;
        const float4 qv = *(const float4*)(qg + base);
        const float4 kv = *(const float4*)(kg + base);
        const int sl = SIG(l);
        zb[0][sl] = make_float2(qv.x, kv.x);
        zb[1][sl] = make_float2(qv.y, kv.y);
        zb[2][sl] = make_float2(qv.z, kv.z);
        zb[3][sl] = make_float2(qv.w, kv.w);
    }
    __syncthreads();
    const int w    = t >> 6;
    const int lane = t & 63;
    float2* Z = zb[w];
    r8_stage<0>(Z, lane);
    r8_stage<3>(Z, lane);
    r8_stage<6>(Z, lane);
    r4_final(Z, lane);
    float sx[32], sy[32];
    #pragma unroll
    for (int i = 0; i < 32; ++i) {
        const int f = lane + (i << 6);
        const float2 zf = Z[SIG(f)];
        const float2 zm = Z[SIG((LN - f) & (LN - 1))];
        const float Qr = 0.5f * (zf.x + zm.x);
        const float Qi = 0.5f * (zf.y - zm.y);
        const float Kr = 0.5f * (zf.y + zm.y);
        const float Ki = -0.5f * (zf.x - zm.x);
        sx[i] = Qr * Kr + Qi * Ki;
        sy[i] = Qi * Kr - Qr * Ki;
    }
    __syncthreads();
    #pragma unroll
    for (int i = 0; i < 32; ++i) {
        const int f = lane + (i << 6);
        Z[SIG(f)] = make_float2(sx[i], sy[i]);
    }
    __syncthreads();
    #pragma unroll
    for (int i = 0; i < 8; ++i) {
        const int f  = t + (i << 8);
        if (f <= 1024) {
            const int sf = SIG(f);
            const float rx = zb[0][sf].x + zb[1][sf].x + zb[2][sf].x + zb[3][sf].x;
            const float ry = zb[0][sf].y + zb[1][sf].y + zb[2][sf].y + zb[3][sf].y;
            atomicAdd(&spec[((size_t)b * LN + f) * 2 + 0], rx);
            atomicAdd(&spec[((size_t)b * LN + f) * 2 + 1], ry);
        }
    }
}

// ---------------------------------------------------------------------------
// Kernel B: per-b inverse transform -> mean corr, top-7 + softmax.
// Spectrum stored Hermitian-half: reflect for f > 1024.
// ---------------------------------------------------------------------------
__device__ __forceinline__ unsigned bitrev11(unsigned x) {
    return __brev(x) >> (32 - LOG2L);
}

__global__ __launch_bounds__(256) void icorr_topk_kernel(
    const float* __restrict__ spec, float* __restrict__ wts, int* __restrict__ tao) {
    __shared__ float2 zbuf[LN];
    __shared__ float2 tw[LN / 2];
    __shared__ float  cr[LN];
    __shared__ float  rv[256];
    __shared__ int    ri[256];
    __shared__ float  topv[KTOP];
    __shared__ int    topi[KTOP];
    const int tid = threadIdx.x;
    const int b   = blockIdx.x;
    for (int p = tid; p < LN / 2; p += 256) {
        float s, c;
        sincosf(-TWO_PI * (float)p / (float)LN, &s, &c);
        tw[p] = make_float2(c, s);
    }
    for (int f = tid; f < LN; f += 256) {
        const int  fs  = (f <= 1024) ? f : (LN - f);
        const float sg = (f <= 1024) ? -1.f : 1.f;   // zbuf = conj(S[f])
        float sr = spec[((size_t)b * LN + fs) * 2 + 0];
        float si = spec[((size_t)b * LN + fs) * 2 + 1];
        zbuf[bitrev11((unsigned)f)] = make_float2(sr, sg * si);
    }
    __syncthreads();
    for (int s = 0; s < LOG2L; ++s) {
        const int half = 1 << s;
        for (int j = tid; j < LN / 2; j += 256) {
            const int grp = j >> s;
            const int pos = j & (half - 1);
            const int i0  = (grp << (s + 1)) + pos;
            const int i1  = i0 + half;
            const float2 w = tw[pos << (LOG2L - 1 - s)];
            float2 a  = zbuf[i0];
            float2 bv = zbuf[i1];
            float tr = w.x * bv.x - w.y * bv.y;
            float ti = w.x * bv.y + w.y * bv.x;
            zbuf[i0] = make_float2(a.x + tr, a.y + ti);
            zbuf[i1] = make_float2(a.x - tr, a.y - ti);
        }
        __syncthreads();
    }
    const float scale = 1.0f / ((float)LN * (float)HE);
    for (int t = tid; t < LN; t += 256) cr[t] = zbuf[t].x * scale;
    __syncthreads();
    for (int it = 0; it < KTOP; ++it) {
        float mv = -INFINITY;
        int   mi = 0;
        for (int t = tid; t < LN; t += 256) {
            float v = cr[t];
            if (v > mv) { mv = v; mi = t; }
        }
        rv[tid] = mv; ri[tid] = mi;
        __syncthreads();
        for (int off = 128; off > 0; off >>= 1) {
            if (tid < off) {
                float ov = rv[tid + off]; int oi = ri[tid + off];
                if (ov > rv[tid] || (ov == rv[tid] && oi < ri[tid])) {
                    rv[tid] = ov; ri[tid] = oi;
                }
            }
            __syncthreads();
        }
        if (tid == 0) {
            topv[it] = rv[0];
            topi[it] = ri[0];
            cr[ri[0]] = -INFINITY;
        }
        __syncthreads();
    }
    if (tid == 0) {
        float m = topv[0];
        float s = 0.f;
        float ex[KTOP];
        for (int j = 0; j < KTOP; ++j) { ex[j] = __expf(topv[j] - m); s += ex[j]; }
        float inv = 1.0f / s;
        for (int j = 0; j < KTOP; ++j) {
            wts[b * 8 + j] = ex[j] * inv;
            tao[b * 8 + j] = topi[j];
        }
    }
}

// ---------------------------------------------------------------------------
// Kernel C: out[b,l,:,:] = sum_j w[b,j] * V[b,(l+tao_j)%L,:,:]
// ---------------------------------------------------------------------------
__global__ __launch_bounds__(256) void gather_kernel(
    const float* __restrict__ v, const float* __restrict__ wts,
    const int* __restrict__ tao, float* __restrict__ out) {
    __shared__ float lw[KTOP];
    __shared__ int   lt[KTOP];
    const int tid = threadIdx.x;
    const int bid = blockIdx.x;
    const int wg  = ((bid & 7) << 11) | (bid >> 3);
    const long long idx = (long long)wg * 256 + tid;
    const int c4 = (int)(idx & 127);
    const int l  = (int)((idx >> 7) & (LN - 1));
    const int b  = (int)(idx >> 18);
    if (tid < KTOP) {
        lw[tid] = wts[b * 8 + tid];
        lt[tid] = tao[b * 8 + tid];
    }
    __syncthreads();
    const float4* v4 = (const float4*)v;
    float4 a = make_float4(0.f, 0.f, 0.f, 0.f);
    #pragma unroll
    for (int j = 0; j < KTOP; ++j) {
        int ls = (l + lt[j]) & (LN - 1);
        float4 x = v4[((size_t)b * LN + ls) * 128 + c4];
        float w = lw[j];
        a.x += w * x.x; a.y += w * x.y; a.z += w * x.z; a.w += w * x.w;
    }
    ((float4*)out)[idx] = a;
}

// ---------------------------------------------------------------------------
extern "C" void kernel_launch(void* const* d_in, const int* in_sizes, int n_in,
                              void* d_out, int out_size, void* d_ws, size_t ws_size,
                              hipStream_t stream) {
    const float* q = (const float*)d_in[0];
    const float* k = (const float*)d_in[1];
    const float* v = (const float*)d_in[2];
    float* out = (float*)d_out;

    const size_t nC   = (size_t)BB * HE * LN;          // complex count, 16.7M
    const size_t need = nC * 4 + (size_t)BB * LN * 2 * 4 + (size_t)BB * 8 * 8;

    if (ws_size >= need) {
        unsigned* z    = (unsigned*)d_ws;              // bf16-packed z: 64 MB
        float*    spec = (float*)(z + nC);
        float*    wts  = spec + (size_t)BB * LN * 2;
        int*      tao  = (int*)(wts + BB * 8);

        hipMemsetAsync(spec, 0, (size_t)BB * LN * 2 * sizeof(float), stream);
        transpose_pack_kernel<<<BB * 32 * 8, 256, 0, stream>>>(q, k, z);
        fft_4step_kernel<<<BB * (HE / 4), 256, 0, stream>>>(z, spec);
        icorr_topk_kernel<<<BB, 256, 0, stream>>>(spec, wts, tao);
        const int n4 = BB * LN * HE / 4;
        gather_kernel<<<n4 / 256, 256, 0, stream>>>(v, wts, tao, out);
    } else {
        float* spec = (float*)d_ws;
        float* wts  = spec + (size_t)BB * LN * 2;
        int*   tao  = (int*)(wts + BB * 8);
        hipMemsetAsync(spec, 0, (size_t)BB * LN * 2 * sizeof(float), stream);
        fft_fused_kernel<<<BB * (HE / 4), 256, 0, stream>>>(q, k, spec);
        icorr_topk_kernel<<<BB, 256, 0, stream>>>(spec, wts, tao);
        const int n4 = BB * LN * HE / 4;
        gather_kernel<<<n4 / 256, 256, 0, stream>>>(v, wts, tao, out);
    }
}

// Round 18
// 162.268 us; speedup vs baseline: 1.0133x; 1.0133x over previous
//
#include <hip/hip_runtime.h>
#include <math.h>

#define LN      2048
#define LOG2L   11
#define BB      16
#define HE      512            // H*E channels
#define KTOP    7              // int(log(2048)) = 7
#define TWO_PI  6.283185307179586f
#define RC      0.70710678118654752f

// XOR swizzle on element index for LDS FFT buffers.
#define SIG(e)  ((e) ^ (((e) >> 5) & 31))

struct c32 { float x, y; };
__device__ __forceinline__ c32 cmul(c32 a, c32 b) {
    return { a.x * b.x - a.y * b.y, a.x * b.y + a.y * b.x };
}
__device__ __forceinline__ c32 cadd(c32 a, c32 b) { return { a.x + b.x, a.y + b.y }; }
__device__ __forceinline__ c32 csub(c32 a, c32 b) { return { a.x - b.x, a.y - b.y }; }

// fp32 -> bf16 (RNE) and packed helpers for the staged z buffer.
__device__ __forceinline__ unsigned short f2bf(float f) {
    unsigned u = __float_as_uint(f);
    u = (u + 0x7FFFu + ((u >> 16) & 1u)) >> 16;
    return (unsigned short)u;
}
__device__ __forceinline__ unsigned pkz(float re, float im) {
    return (unsigned)f2bf(re) | ((unsigned)f2bf(im) << 16);
}

__device__ __forceinline__ void dft4(c32 a, c32 b, c32 c, c32 d,
                                     c32& y0, c32& y1, c32& y2, c32& y3) {
    c32 t0 = cadd(a, c), t1 = csub(a, c);
    c32 t2 = cadd(b, d);
    c32 t3 = { b.y - d.y, d.x - b.x };          // -i*(b-d)
    y0 = cadd(t0, t2);
    y1 = cadd(t1, t3);
    y2 = csub(t0, t2);
    y3 = csub(t1, t3);
}

__device__ __forceinline__ void dft8(const c32* x, c32* y) {
    c32 e0, e1, e2, e3, o0, o1, o2, o3;
    dft4(x[0], x[2], x[4], x[6], e0, e1, e2, e3);
    dft4(x[1], x[3], x[5], x[7], o0, o1, o2, o3);
    c32 p1 = { RC * (o1.x + o1.y), RC * (o1.y - o1.x) };
    c32 p2 = { o2.y, -o2.x };
    c32 p3 = { RC * (o3.y - o3.x), -RC * (o3.x + o3.y) };
    y[0] = cadd(e0, o0); y[4] = csub(e0, o0);
    y[1] = cadd(e1, p1); y[5] = csub(e1, p1);
    y[2] = cadd(e2, p2); y[6] = csub(e2, p2);
    y[3] = cadd(e3, p3); y[7] = csub(e3, p3);
}

// Twiddle set for one stage: W[k-1] = W_2048^{pm*k}, k=1..7 (tree, depth<=2).
__device__ __forceinline__ void mk_tw(int pm, c32* W) {
    float sn, cs;
    __sincosf(-(TWO_PI / (float)LN) * (float)pm, &sn, &cs);
    const c32 w1 = { cs, sn };
    const c32 w2 = cmul(w1, w1);
    const c32 w3 = cmul(w1, w2);
    const c32 w4 = cmul(w2, w2);
    W[0] = w1; W[1] = w2; W[2] = w3; W[3] = w4;
    W[4] = cmul(w1, w4); W[5] = cmul(w2, w4); W[6] = cmul(w3, w4);
}

// Whole-WG Stockham DIF radix-8 stage from LDS, twiddles pre-hoisted.
template<int LOG2M>
__device__ __forceinline__ void r8_ld(float2* Z, int tid, const c32* TW) {
    c32 v[8];
    #pragma unroll
    for (int r = 0; r < 8; ++r) {
        float2 z = Z[SIG(tid + (r << 8))];
        v[r] = { z.x, z.y };
    }
    c32 y[8];
    dft8(v, y);
    #pragma unroll
    for (int kk = 1; kk < 8; ++kk) y[kk] = cmul(y[kk], TW[kk - 1]);
    __syncthreads();
    const int q_ = tid & ((1 << LOG2M) - 1);
    const int ob = q_ + ((tid - q_) << 3);       // q + 8*m*p
    #pragma unroll
    for (int kk = 0; kk < 8; ++kk)
        Z[SIG(ob + (kk << LOG2M))] = make_float2(y[kk].x, y[kk].y);
    __syncthreads();
}

// Final radix-4 stage, m=512 (twiddle-free), 512 butterflies / 256 threads.
__device__ __forceinline__ void r4_final_wg(float2* Z, int tid) {
    c32 v[2][4];
    #pragma unroll
    for (int u = 0; u < 2; ++u) {
        const int j = tid + (u << 8);
        #pragma unroll
        for (int r = 0; r < 4; ++r) {
            float2 z = Z[SIG(j + (r << 9))];
            v[u][r] = { z.x, z.y };
        }
    }
    __syncthreads();
    #pragma unroll
    for (int u = 0; u < 2; ++u) {
        const int j = tid + (u << 8);
        c32 y0, y1, y2, y3;
        dft4(v[u][0], v[u][1], v[u][2], v[u][3], y0, y1, y2, y3);
        Z[SIG(j)]        = make_float2(y0.x, y0.y);
        Z[SIG(j + 512)]  = make_float2(y1.x, y1.y);
        Z[SIG(j + 1024)] = make_float2(y2.x, y2.y);
        Z[SIG(j + 1536)] = make_float2(y3.x, y3.y);
    }
    __syncthreads();
}

// ---------------------------------------------------------------------------
// Kernel T v5: coalesced transpose with bf16 packing AT LOAD — uint LDS
// tile (16.6 KB vs 33 KB) doubles resident WGs/CU. float4 global loads,
// uint4 LDS writes, uint4 global stores.
// ---------------------------------------------------------------------------
__global__ __launch_bounds__(256) void transpose_pack_kernel(
    const float* __restrict__ q, const float* __restrict__ k,
    unsigned* __restrict__ z) {
    __shared__ unsigned tile[64][65];        // bf16-packed z, 16.6 KB
    const int tid = threadIdx.x;
    const int bid = blockIdx.x;
    const int b  = bid >> 8;
    const int lt = (bid >> 3) & 31;
    const int ct = bid & 7;
    const int l0 = lt << 6, c0 = ct << 6;
    const int g16 = tid >> 4;               // 0..15
    const int m16 = (tid & 15) << 2;        // 0,4,..,60
    #pragma unroll
    for (int ii = 0; ii < 4; ++ii) {
        const int r = g16 + (ii << 4);      // l offset 0..63
        const size_t src = ((size_t)(b * LN + l0 + r)) * HE + c0 + m16;
        const float4 qv = *(const float4*)(q + src);
        const float4 kv = *(const float4*)(k + src);
        uint4 t;
        t.x = pkz(qv.x, kv.x);
        t.y = pkz(qv.y, kv.y);
        t.z = pkz(qv.z, kv.z);
        t.w = pkz(qv.w, kv.w);
        *(uint4*)&tile[r][m16] = t;
    }
    __syncthreads();
    #pragma unroll
    for (int ii = 0; ii < 4; ++ii) {
        const int rc = g16 + (ii << 4);     // c offset 0..63
        uint4 w;
        w.x = tile[m16 + 0][rc];
        w.y = tile[m16 + 1][rc];
        w.z = tile[m16 + 2][rc];
        w.w = tile[m16 + 3][rc];
        unsigned* dst = z + ((size_t)(b * HE + c0 + rc)) * LN + l0 + m16;
        *(uint4*)dst = w;
    }
}

// ---------------------------------------------------------------------------
// Kernel A: r16 FFT (best measured: 74 us). Stage-0 from bf16-packed global,
// hoisted twiddle trees, Hermitian-half flush, b = wg>>7 L2 locality.
// ---------------------------------------------------------------------------
__global__ __launch_bounds__(256) void fft_reg0_kernel(
    const unsigned* __restrict__ z,
    float* __restrict__ spec /* [BB][LN][2], only f<=1024 written */) {
    __shared__ float2 Z[LN];                     // 16 KB
    const int tid = threadIdx.x;
    const int wg  = blockIdx.x;                  // 2048
    const int b   = wg >> 7;                     // L2-locality mapping
    const int c0  = (wg & 127) << 2;

    c32 TW0[7], TW1[7], TW2[7];                  // channel-invariant
    mk_tw(tid, TW0);
    mk_tw(tid & ~7, TW1);
    mk_tw(tid & ~63, TW2);

    float accx[4], accy[4];
    #pragma unroll
    for (int i = 0; i < 4; ++i) { accx[i] = 0.f; accy[i] = 0.f; }
    float a1024 = 0.f;

    #pragma unroll 1
    for (int ch = 0; ch < 4; ++ch) {
        const unsigned* zc = z + (((size_t)(b * HE + c0 + ch)) << LOG2L);
        // stage 0 straight from global: 1 dword per complex, coalesced
        c32 v[8];
        #pragma unroll
        for (int r = 0; r < 8; ++r) {
            const unsigned u = zc[tid + (r << 8)];
            v[r].x = __uint_as_float(u << 16);
            v[r].y = __uint_as_float(u & 0xFFFF0000u);
        }
        c32 y[8];
        dft8(v, y);
        #pragma unroll
        for (int kk = 1; kk < 8; ++kk) y[kk] = cmul(y[kk], TW0[kk - 1]);
        __syncthreads();                         // Z free (prev unpack done)
        #pragma unroll
        for (int kk = 0; kk < 8; ++kk)           // ob = 8*tid, contiguous
            Z[SIG((tid << 3) + kk)] = make_float2(y[kk].x, y[kk].y);
        __syncthreads();

        r8_ld<3>(Z, tid, TW1);
        r8_ld<6>(Z, tid, TW2);
        r4_final_wg(Z, tid);

        // Hermitian-half unpack: S = Q*conj(K), f in [0,1024)
        #pragma unroll
        for (int i = 0; i < 4; ++i) {
            const int f = tid + (i << 8);
            const int g = (LN - f) & (LN - 1);
            const float2 zf = Z[SIG(f)];
            const float2 zm = Z[SIG(g)];
            const float Qr = 0.5f * (zf.x + zm.x);
            const float Qi = 0.5f * (zf.y - zm.y);
            const float Kr = 0.5f * (zf.y + zm.y);
            const float Ki = -0.5f * (zf.x - zm.x);
            accx[i] += Qr * Kr + Qi * Ki;
            accy[i] += Qi * Kr - Qr * Ki;
        }
        if (tid == 0) {                          // f = 1024: S real
            const float2 zf = Z[SIG(1024)];
            a1024 += zf.x * zf.y;
        }
    }
    #pragma unroll
    for (int i = 0; i < 4; ++i) {
        const int f = tid + (i << 8);
        atomicAdd(&spec[((size_t)b * LN + f) * 2 + 0], accx[i]);
        atomicAdd(&spec[((size_t)b * LN + f) * 2 + 1], accy[i]);
    }
    if (tid == 0)
        atomicAdd(&spec[((size_t)b * LN + 1024) * 2 + 0], a1024);
}

// ---------------------------------------------------------------------------
// Fallback (raw fp32 layout, round-3 path; flush gated to f<=1024) — only if
// ws is too small for the packed staging buffer.
// ---------------------------------------------------------------------------
template<int LOG2M>
__device__ __forceinline__ void r8_stage(float2* Z, int lane) {
    c32 v[32];
    #pragma unroll
    for (int u = 0; u < 4; ++u) {
        const int j = lane + (u << 6);
        #pragma unroll
        for (int r = 0; r < 8; ++r) {
            float2 z = Z[SIG(j + (r << 8))];
            v[(u << 3) + r] = { z.x, z.y };
        }
    }
    c32 y[32];
    #pragma unroll
    for (int u = 0; u < 4; ++u) {
        const int j  = lane + (u << 6);
        const int pm = j & ~((1 << LOG2M) - 1);
        dft8(&v[u << 3], &y[u << 3]);
        float sn, cs;
        __sincosf(-(TWO_PI / (float)LN) * (float)pm, &sn, &cs);
        c32 base = { cs, sn };
        c32 t = base;
        #pragma unroll
        for (int kk = 1; kk < 8; ++kk) {
            y[(u << 3) + kk] = cmul(y[(u << 3) + kk], t);
            if (kk < 7) t = cmul(t, base);
        }
    }
    __syncthreads();
    #pragma unroll
    for (int u = 0; u < 4; ++u) {
        const int j  = lane + (u << 6);
        const int q_ = j & ((1 << LOG2M) - 1);
        const int ob = q_ + ((j - q_) << 3);
        #pragma unroll
        for (int kk = 0; kk < 8; ++kk) {
            c32 yy = y[(u << 3) + kk];
            Z[SIG(ob + (kk << LOG2M))] = make_float2(yy.x, yy.y);
        }
    }
    __syncthreads();
}

__device__ __forceinline__ void r4_final(float2* Z, int lane) {
    c32 v[32];
    #pragma unroll
    for (int u = 0; u < 8; ++u) {
        const int j = lane + (u << 6);
        #pragma unroll
        for (int r = 0; r < 4; ++r) {
            float2 z = Z[SIG(j + (r << 9))];
            v[(u << 2) + r] = { z.x, z.y };
        }
    }
    __syncthreads();
    #pragma unroll
    for (int u = 0; u < 8; ++u) {
        const int j = lane + (u << 6);
        c32 y0, y1, y2, y3;
        dft4(v[u << 2], v[(u << 2) + 1], v[(u << 2) + 2], v[(u << 2) + 3],
             y0, y1, y2, y3);
        Z[SIG(j)]        = make_float2(y0.x, y0.y);
        Z[SIG(j + 512)]  = make_float2(y1.x, y1.y);
        Z[SIG(j + 1024)] = make_float2(y2.x, y2.y);
        Z[SIG(j + 1536)] = make_float2(y3.x, y3.y);
    }
    __syncthreads();
}

__global__ __launch_bounds__(256) void fft_fused_kernel(
    const float* __restrict__ qg, const float* __restrict__ kg,
    float* __restrict__ spec) {
    __shared__ float2 zb[4][LN];
    const int t    = threadIdx.x;
    const int bid  = blockIdx.x;
    const int wgid = ((bid & 7) << 8) | (bid >> 3);
    const int b    = wgid >> 7;
    const int c0   = (wgid & 127) << 2;
    #pragma unroll
    for (int i = 0; i < 8; ++i) {
        const int l = t + (i << 8);
        const size_t base = (size_t)(b * LN + l) * HE + c0;
        const float4 qv = *(const float4*)(qg + base);
        const float4 kv = *(const float4*)(kg + base);
        const int sl = SIG(l);
        zb[0][sl] = make_float2(qv.x, kv.x);
        zb[1][sl] = make_float2(qv.y, kv.y);
        zb[2][sl] = make_float2(qv.z, kv.z);
        zb[3][sl] = make_float2(qv.w, kv.w);
    }
    __syncthreads();
    const int w    = t >> 6;
    const int lane = t & 63;
    float2* Z = zb[w];
    r8_stage<0>(Z, lane);
    r8_stage<3>(Z, lane);
    r8_stage<6>(Z, lane);
    r4_final(Z, lane);
    float sx[32], sy[32];
    #pragma unroll
    for (int i = 0; i < 32; ++i) {
        const int f = lane + (i << 6);
        const float2 zf = Z[SIG(f)];
        const float2 zm = Z[SIG((LN - f) & (LN - 1))];
        const float Qr = 0.5f * (zf.x + zm.x);
        const float Qi = 0.5f * (zf.y - zm.y);
        const float Kr = 0.5f * (zf.y + zm.y);
        const float Ki = -0.5f * (zf.x - zm.x);
        sx[i] = Qr * Kr + Qi * Ki;
        sy[i] = Qi * Kr - Qr * Ki;
    }
    __syncthreads();
    #pragma unroll
    for (int i = 0; i < 32; ++i) {
        const int f = lane + (i << 6);
        Z[SIG(f)] = make_float2(sx[i], sy[i]);
    }
    __syncthreads();
    #pragma unroll
    for (int i = 0; i < 8; ++i) {
        const int f  = t + (i << 8);
        if (f <= 1024) {
            const int sf = SIG(f);
            const float rx = zb[0][sf].x + zb[1][sf].x + zb[2][sf].x + zb[3][sf].x;
            const float ry = zb[0][sf].y + zb[1][sf].y + zb[2][sf].y + zb[3][sf].y;
            atomicAdd(&spec[((size_t)b * LN + f) * 2 + 0], rx);
            atomicAdd(&spec[((size_t)b * LN + f) * 2 + 1], ry);
        }
    }
}

// ---------------------------------------------------------------------------
// Kernel B: per-b inverse transform -> mean corr, top-7 + softmax.
// Spectrum stored Hermitian-half: reflect for f > 1024.
// ---------------------------------------------------------------------------
__device__ __forceinline__ unsigned bitrev11(unsigned x) {
    return __brev(x) >> (32 - LOG2L);
}

__global__ __launch_bounds__(256) void icorr_topk_kernel(
    const float* __restrict__ spec, float* __restrict__ wts, int* __restrict__ tao) {
    __shared__ float2 zbuf[LN];
    __shared__ float2 tw[LN / 2];
    __shared__ float  cr[LN];
    __shared__ float  rv[256];
    __shared__ int    ri[256];
    __shared__ float  topv[KTOP];
    __shared__ int    topi[KTOP];
    const int tid = threadIdx.x;
    const int b   = blockIdx.x;
    for (int p = tid; p < LN / 2; p += 256) {
        float s, c;
        sincosf(-TWO_PI * (float)p / (float)LN, &s, &c);
        tw[p] = make_float2(c, s);
    }
    for (int f = tid; f < LN; f += 256) {
        const int  fs  = (f <= 1024) ? f : (LN - f);
        const float sg = (f <= 1024) ? -1.f : 1.f;   // zbuf = conj(S[f])
        float sr = spec[((size_t)b * LN + fs) * 2 + 0];
        float si = spec[((size_t)b * LN + fs) * 2 + 1];
        zbuf[bitrev11((unsigned)f)] = make_float2(sr, sg * si);
    }
    __syncthreads();
    for (int s = 0; s < LOG2L; ++s) {
        const int half = 1 << s;
        for (int j = tid; j < LN / 2; j += 256) {
            const int grp = j >> s;
            const int pos = j & (half - 1);
            const int i0  = (grp << (s + 1)) + pos;
            const int i1  = i0 + half;
            const float2 w = tw[pos << (LOG2L - 1 - s)];
            float2 a  = zbuf[i0];
            float2 bv = zbuf[i1];
            float tr = w.x * bv.x - w.y * bv.y;
            float ti = w.x * bv.y + w.y * bv.x;
            zbuf[i0] = make_float2(a.x + tr, a.y + ti);
            zbuf[i1] = make_float2(a.x - tr, a.y - ti);
        }
        __syncthreads();
    }
    const float scale = 1.0f / ((float)LN * (float)HE);
    for (int t = tid; t < LN; t += 256) cr[t] = zbuf[t].x * scale;
    __syncthreads();
    for (int it = 0; it < KTOP; ++it) {
        float mv = -INFINITY;
        int   mi = 0;
        for (int t = tid; t < LN; t += 256) {
            float v = cr[t];
            if (v > mv) { mv = v; mi = t; }
        }
        rv[tid] = mv; ri[tid] = mi;
        __syncthreads();
        for (int off = 128; off > 0; off >>= 1) {
            if (tid < off) {
                float ov = rv[tid + off]; int oi = ri[tid + off];
                if (ov > rv[tid] || (ov == rv[tid] && oi < ri[tid])) {
                    rv[tid] = ov; ri[tid] = oi;
                }
            }
            __syncthreads();
        }
        if (tid == 0) {
            topv[it] = rv[0];
            topi[it] = ri[0];
            cr[ri[0]] = -INFINITY;
        }
        __syncthreads();
    }
    if (tid == 0) {
        float m = topv[0];
        float s = 0.f;
        float ex[KTOP];
        for (int j = 0; j < KTOP; ++j) { ex[j] = __expf(topv[j] - m); s += ex[j]; }
        float inv = 1.0f / s;
        for (int j = 0; j < KTOP; ++j) {
            wts[b * 8 + j] = ex[j] * inv;
            tao[b * 8 + j] = topi[j];
        }
    }
}

// ---------------------------------------------------------------------------
// Kernel C: out[b,l,:,:] = sum_j w[b,j] * V[b,(l+tao_j)%L,:,:]
// ---------------------------------------------------------------------------
__global__ __launch_bounds__(256) void gather_kernel(
    const float* __restrict__ v, const float* __restrict__ wts,
    const int* __restrict__ tao, float* __restrict__ out) {
    __shared__ float lw[KTOP];
    __shared__ int   lt[KTOP];
    const int tid = threadIdx.x;
    const int bid = blockIdx.x;
    const int wg  = ((bid & 7) << 11) | (bid >> 3);
    const long long idx = (long long)wg * 256 + tid;
    const int c4 = (int)(idx & 127);
    const int l  = (int)((idx >> 7) & (LN - 1));
    const int b  = (int)(idx >> 18);
    if (tid < KTOP) {
        lw[tid] = wts[b * 8 + tid];
        lt[tid] = tao[b * 8 + tid];
    }
    __syncthreads();
    const float4* v4 = (const float4*)v;
    float4 a = make_float4(0.f, 0.f, 0.f, 0.f);
    #pragma unroll
    for (int j = 0; j < KTOP; ++j) {
        int ls = (l + lt[j]) & (LN - 1);
        float4 x = v4[((size_t)b * LN + ls) * 128 + c4];
        float w = lw[j];
        a.x += w * x.x; a.y += w * x.y; a.z += w * x.z; a.w += w * x.w;
    }
    ((float4*)out)[idx] = a;
}

// ---------------------------------------------------------------------------
extern "C" void kernel_launch(void* const* d_in, const int* in_sizes, int n_in,
                              void* d_out, int out_size, void* d_ws, size_t ws_size,
                              hipStream_t stream) {
    const float* q = (const float*)d_in[0];
    const float* k = (const float*)d_in[1];
    const float* v = (const float*)d_in[2];
    float* out = (float*)d_out;

    const size_t nC   = (size_t)BB * HE * LN;          // complex count, 16.7M
    const size_t need = nC * 4 + (size_t)BB * LN * 2 * 4 + (size_t)BB * 8 * 8;

    if (ws_size >= need) {
        unsigned* z    = (unsigned*)d_ws;              // bf16-packed z: 64 MB
        float*    spec = (float*)(z + nC);
        float*    wts  = spec + (size_t)BB * LN * 2;
        int*      tao  = (int*)(wts + BB * 8);

        hipMemsetAsync(spec, 0, (size_t)BB * LN * 2 * sizeof(float), stream);
        transpose_pack_kernel<<<BB * 32 * 8, 256, 0, stream>>>(q, k, z);
        fft_reg0_kernel<<<BB * (HE / 4), 256, 0, stream>>>(z, spec);
        icorr_topk_kernel<<<BB, 256, 0, stream>>>(spec, wts, tao);
        const int n4 = BB * LN * HE / 4;
        gather_kernel<<<n4 / 256, 256, 0, stream>>>(v, wts, tao, out);
    } else {
        float* spec = (float*)d_ws;
        float* wts  = spec + (size_t)BB * LN * 2;
        int*   tao  = (int*)(wts + BB * 8);
        hipMemsetAsync(spec, 0, (size_t)BB * LN * 2 * sizeof(float), stream);
        fft_fused_kernel<<<BB * (HE / 4), 256, 0, stream>>>(q, k, spec);
        icorr_topk_kernel<<<BB, 256, 0, stream>>>(spec, wts, tao);
        const int n4 = BB * LN * HE / 4;
        gather_kernel<<<n4 / 256, 256, 0, stream>>>(v, wts, tao, out);
    }
}

// Round 19
// 157.629 us; speedup vs baseline: 1.0431x; 1.0294x over previous
//
#include <hip/hip_runtime.h>
#include <math.h>

#define LN      2048
#define LOG2L   11
#define BB      16
#define HE      512            // H*E channels
#define KTOP    7              // int(log(2048)) = 7
#define TWO_PI  6.283185307179586f
#define RC      0.70710678118654752f

// XOR swizzle on element index for LDS FFT buffers.
#define SIG(e)  ((e) ^ (((e) >> 5) & 31))

struct c32 { float x, y; };
__device__ __forceinline__ c32 cmul(c32 a, c32 b) {
    return { a.x * b.x - a.y * b.y, a.x * b.y + a.y * b.x };
}
__device__ __forceinline__ c32 cadd(c32 a, c32 b) { return { a.x + b.x, a.y + b.y }; }
__device__ __forceinline__ c32 csub(c32 a, c32 b) { return { a.x - b.x, a.y - b.y }; }

// fp32 -> bf16 (RNE) and packed helpers for the staged z buffer.
__device__ __forceinline__ unsigned short f2bf(float f) {
    unsigned u = __float_as_uint(f);
    u = (u + 0x7FFFu + ((u >> 16) & 1u)) >> 16;
    return (unsigned short)u;
}
__device__ __forceinline__ unsigned pkz(float re, float im) {
    return (unsigned)f2bf(re) | ((unsigned)f2bf(im) << 16);
}

__device__ __forceinline__ void dft4(c32 a, c32 b, c32 c, c32 d,
                                     c32& y0, c32& y1, c32& y2, c32& y3) {
    c32 t0 = cadd(a, c), t1 = csub(a, c);
    c32 t2 = cadd(b, d);
    c32 t3 = { b.y - d.y, d.x - b.x };          // -i*(b-d)
    y0 = cadd(t0, t2);
    y1 = cadd(t1, t3);
    y2 = csub(t0, t2);
    y3 = csub(t1, t3);
}

__device__ __forceinline__ void dft8(const c32* x, c32* y) {
    c32 e0, e1, e2, e3, o0, o1, o2, o3;
    dft4(x[0], x[2], x[4], x[6], e0, e1, e2, e3);
    dft4(x[1], x[3], x[5], x[7], o0, o1, o2, o3);
    c32 p1 = { RC * (o1.x + o1.y), RC * (o1.y - o1.x) };
    c32 p2 = { o2.y, -o2.x };
    c32 p3 = { RC * (o3.y - o3.x), -RC * (o3.x + o3.y) };
    y[0] = cadd(e0, o0); y[4] = csub(e0, o0);
    y[1] = cadd(e1, p1); y[5] = csub(e1, p1);
    y[2] = cadd(e2, p2); y[6] = csub(e2, p2);
    y[3] = cadd(e3, p3); y[7] = csub(e3, p3);
}

// Twiddle set for one stage: W[k-1] = W_2048^{pm*k}, k=1..7 (tree, depth<=2).
__device__ __forceinline__ void mk_tw(int pm, c32* W) {
    float sn, cs;
    __sincosf(-(TWO_PI / (float)LN) * (float)pm, &sn, &cs);
    const c32 w1 = { cs, sn };
    const c32 w2 = cmul(w1, w1);
    const c32 w3 = cmul(w1, w2);
    const c32 w4 = cmul(w2, w2);
    W[0] = w1; W[1] = w2; W[2] = w3; W[3] = w4;
    W[4] = cmul(w1, w4); W[5] = cmul(w2, w4); W[6] = cmul(w3, w4);
}

// Whole-WG Stockham DIF radix-8 stage from LDS, twiddles pre-hoisted.
template<int LOG2M>
__device__ __forceinline__ void r8_ld(float2* Z, int tid, const c32* TW) {
    c32 v[8];
    #pragma unroll
    for (int r = 0; r < 8; ++r) {
        float2 z = Z[SIG(tid + (r << 8))];
        v[r] = { z.x, z.y };
    }
    c32 y[8];
    dft8(v, y);
    #pragma unroll
    for (int kk = 1; kk < 8; ++kk) y[kk] = cmul(y[kk], TW[kk - 1]);
    __syncthreads();
    const int q_ = tid & ((1 << LOG2M) - 1);
    const int ob = q_ + ((tid - q_) << 3);       // q + 8*m*p
    #pragma unroll
    for (int kk = 0; kk < 8; ++kk)
        Z[SIG(ob + (kk << LOG2M))] = make_float2(y[kk].x, y[kk].y);
    __syncthreads();
}

// Final radix-4 stage, m=512 (twiddle-free), 512 butterflies / 256 threads.
__device__ __forceinline__ void r4_final_wg(float2* Z, int tid) {
    c32 v[2][4];
    #pragma unroll
    for (int u = 0; u < 2; ++u) {
        const int j = tid + (u << 8);
        #pragma unroll
        for (int r = 0; r < 4; ++r) {
            float2 z = Z[SIG(j + (r << 9))];
            v[u][r] = { z.x, z.y };
        }
    }
    __syncthreads();
    #pragma unroll
    for (int u = 0; u < 2; ++u) {
        const int j = tid + (u << 8);
        c32 y0, y1, y2, y3;
        dft4(v[u][0], v[u][1], v[u][2], v[u][3], y0, y1, y2, y3);
        Z[SIG(j)]        = make_float2(y0.x, y0.y);
        Z[SIG(j + 512)]  = make_float2(y1.x, y1.y);
        Z[SIG(j + 1024)] = make_float2(y2.x, y2.y);
        Z[SIG(j + 1536)] = make_float2(y3.x, y3.y);
    }
    __syncthreads();
}

// ---------------------------------------------------------------------------
// Kernel T v6: coalesced transpose with bf16 packing at load (uint LDS tile,
// 16.6 KB). ALSO zeroes spec (first 64 WGs) so the separate memset dispatch
// is removed — kernel boundary orders it before fft's atomics.
// ---------------------------------------------------------------------------
__global__ __launch_bounds__(256) void transpose_pack_kernel(
    const float* __restrict__ q, const float* __restrict__ k,
    unsigned* __restrict__ z, float* __restrict__ spec) {
    __shared__ unsigned tile[64][65];        // bf16-packed z, 16.6 KB
    const int tid = threadIdx.x;
    const int bid = blockIdx.x;
    if (bid < 64) {                          // zero spec: 64*256 float4 = 256KB
        ((float4*)spec)[(bid << 8) | tid] = make_float4(0.f, 0.f, 0.f, 0.f);
    }
    const int b  = bid >> 8;
    const int lt = (bid >> 3) & 31;
    const int ct = bid & 7;
    const int l0 = lt << 6, c0 = ct << 6;
    const int g16 = tid >> 4;               // 0..15
    const int m16 = (tid & 15) << 2;        // 0,4,..,60
    #pragma unroll
    for (int ii = 0; ii < 4; ++ii) {
        const int r = g16 + (ii << 4);      // l offset 0..63
        const size_t src = ((size_t)(b * LN + l0 + r)) * HE + c0 + m16;
        const float4 qv = *(const float4*)(q + src);
        const float4 kv = *(const float4*)(k + src);
        uint4 t;
        t.x = pkz(qv.x, kv.x);
        t.y = pkz(qv.y, kv.y);
        t.z = pkz(qv.z, kv.z);
        t.w = pkz(qv.w, kv.w);
        *(uint4*)&tile[r][m16] = t;
    }
    __syncthreads();
    #pragma unroll
    for (int ii = 0; ii < 4; ++ii) {
        const int rc = g16 + (ii << 4);     // c offset 0..63
        uint4 w;
        w.x = tile[m16 + 0][rc];
        w.y = tile[m16 + 1][rc];
        w.z = tile[m16 + 2][rc];
        w.w = tile[m16 + 3][rc];
        unsigned* dst = z + ((size_t)(b * HE + c0 + rc)) * LN + l0 + m16;
        *(uint4*)dst = w;
    }
}

// ---------------------------------------------------------------------------
// Kernel A: r16 FFT (best measured: 74 us). Stage-0 from bf16-packed global,
// hoisted twiddle trees, Hermitian-half flush, b = wg>>7 L2 locality.
// ---------------------------------------------------------------------------
__global__ __launch_bounds__(256) void fft_reg0_kernel(
    const unsigned* __restrict__ z,
    float* __restrict__ spec /* [BB][LN][2], only f<=1024 written */) {
    __shared__ float2 Z[LN];                     // 16 KB
    const int tid = threadIdx.x;
    const int wg  = blockIdx.x;                  // 2048
    const int b   = wg >> 7;                     // L2-locality mapping
    const int c0  = (wg & 127) << 2;

    c32 TW0[7], TW1[7], TW2[7];                  // channel-invariant
    mk_tw(tid, TW0);
    mk_tw(tid & ~7, TW1);
    mk_tw(tid & ~63, TW2);

    float accx[4], accy[4];
    #pragma unroll
    for (int i = 0; i < 4; ++i) { accx[i] = 0.f; accy[i] = 0.f; }
    float a1024 = 0.f;

    #pragma unroll 1
    for (int ch = 0; ch < 4; ++ch) {
        const unsigned* zc = z + (((size_t)(b * HE + c0 + ch)) << LOG2L);
        // stage 0 straight from global: 1 dword per complex, coalesced
        c32 v[8];
        #pragma unroll
        for (int r = 0; r < 8; ++r) {
            const unsigned u = zc[tid + (r << 8)];
            v[r].x = __uint_as_float(u << 16);
            v[r].y = __uint_as_float(u & 0xFFFF0000u);
        }
        c32 y[8];
        dft8(v, y);
        #pragma unroll
        for (int kk = 1; kk < 8; ++kk) y[kk] = cmul(y[kk], TW0[kk - 1]);
        __syncthreads();                         // Z free (prev unpack done)
        #pragma unroll
        for (int kk = 0; kk < 8; ++kk)           // ob = 8*tid, contiguous
            Z[SIG((tid << 3) + kk)] = make_float2(y[kk].x, y[kk].y);
        __syncthreads();

        r8_ld<3>(Z, tid, TW1);
        r8_ld<6>(Z, tid, TW2);
        r4_final_wg(Z, tid);

        // Hermitian-half unpack: S = Q*conj(K), f in [0,1024)
        #pragma unroll
        for (int i = 0; i < 4; ++i) {
            const int f = tid + (i << 8);
            const int g = (LN - f) & (LN - 1);
            const float2 zf = Z[SIG(f)];
            const float2 zm = Z[SIG(g)];
            const float Qr = 0.5f * (zf.x + zm.x);
            const float Qi = 0.5f * (zf.y - zm.y);
            const float Kr = 0.5f * (zf.y + zm.y);
            const float Ki = -0.5f * (zf.x - zm.x);
            accx[i] += Qr * Kr + Qi * Ki;
            accy[i] += Qi * Kr - Qr * Ki;
        }
        if (tid == 0) {                          // f = 1024: S real
            const float2 zf = Z[SIG(1024)];
            a1024 += zf.x * zf.y;
        }
    }
    #pragma unroll
    for (int i = 0; i < 4; ++i) {
        const int f = tid + (i << 8);
        atomicAdd(&spec[((size_t)b * LN + f) * 2 + 0], accx[i]);
        atomicAdd(&spec[((size_t)b * LN + f) * 2 + 1], accy[i]);
    }
    if (tid == 0)
        atomicAdd(&spec[((size_t)b * LN + 1024) * 2 + 0], a1024);
}

// ---------------------------------------------------------------------------
// Fallback (raw fp32 layout, round-3 path; flush gated to f<=1024) — only if
// ws is too small for the packed staging buffer.
// ---------------------------------------------------------------------------
template<int LOG2M>
__device__ __forceinline__ void r8_stage(float2* Z, int lane) {
    c32 v[32];
    #pragma unroll
    for (int u = 0; u < 4; ++u) {
        const int j = lane + (u << 6);
        #pragma unroll
        for (int r = 0; r < 8; ++r) {
            float2 z = Z[SIG(j + (r << 8))];
            v[(u << 3) + r] = { z.x, z.y };
        }
    }
    c32 y[32];
    #pragma unroll
    for (int u = 0; u < 4; ++u) {
        const int j  = lane + (u << 6);
        const int pm = j & ~((1 << LOG2M) - 1);
        dft8(&v[u << 3], &y[u << 3]);
        float sn, cs;
        __sincosf(-(TWO_PI / (float)LN) * (float)pm, &sn, &cs);
        c32 base = { cs, sn };
        c32 t = base;
        #pragma unroll
        for (int kk = 1; kk < 8; ++kk) {
            y[(u << 3) + kk] = cmul(y[(u << 3) + kk], t);
            if (kk < 7) t = cmul(t, base);
        }
    }
    __syncthreads();
    #pragma unroll
    for (int u = 0; u < 4; ++u) {
        const int j  = lane + (u << 6);
        const int q_ = j & ((1 << LOG2M) - 1);
        const int ob = q_ + ((j - q_) << 3);
        #pragma unroll
        for (int kk = 0; kk < 8; ++kk) {
            c32 yy = y[(u << 3) + kk];
            Z[SIG(ob + (kk << LOG2M))] = make_float2(yy.x, yy.y);
        }
    }
    __syncthreads();
}

__device__ __forceinline__ void r4_final(float2* Z, int lane) {
    c32 v[32];
    #pragma unroll
    for (int u = 0; u < 8; ++u) {
        const int j = lane + (u << 6);
        #pragma unroll
        for (int r = 0; r < 4; ++r) {
            float2 z = Z[SIG(j + (r << 9))];
            v[(u << 2) + r] = { z.x, z.y };
        }
    }
    __syncthreads();
    #pragma unroll
    for (int u = 0; u < 8; ++u) {
        const int j = lane + (u << 6);
        c32 y0, y1, y2, y3;
        dft4(v[u << 2], v[(u << 2) + 1], v[(u << 2) + 2], v[(u << 2) + 3],
             y0, y1, y2, y3);
        Z[SIG(j)]        = make_float2(y0.x, y0.y);
        Z[SIG(j + 512)]  = make_float2(y1.x, y1.y);
        Z[SIG(j + 1024)] = make_float2(y2.x, y2.y);
        Z[SIG(j + 1536)] = make_float2(y3.x, y3.y);
    }
    __syncthreads();
}

__global__ __launch_bounds__(256) void fft_fused_kernel(
    const float* __restrict__ qg, const float* __restrict__ kg,
    float* __restrict__ spec) {
    __shared__ float2 zb[4][LN];
    const int t    = threadIdx.x;
    const int bid  = blockIdx.x;
    const int wgid = ((bid & 7) << 8) | (bid >> 3);
    const int b    = wgid >> 7;
    const int c0   = (wgid & 127) << 2;
    #pragma unroll
    for (int i = 0; i < 8; ++i) {
        const int l = t + (i << 8);
        const size_t base = (size_t)(b * LN + l) * HE + c0;
        const float4 qv = *(const float4*)(qg + base);
        const float4 kv = *(const float4*)(kg + base);
        const int sl = SIG(l);
        zb[0][sl] = make_float2(qv.x, kv.x);
        zb[1][sl] = make_float2(qv.y, kv.y);
        zb[2][sl] = make_float2(qv.z, kv.z);
        zb[3][sl] = make_float2(qv.w, kv.w);
    }
    __syncthreads();
    const int w    = t >> 6;
    const int lane = t & 63;
    float2* Z = zb[w];
    r8_stage<0>(Z, lane);
    r8_stage<3>(Z, lane);
    r8_stage<6>(Z, lane);
    r4_final(Z, lane);
    float sx[32], sy[32];
    #pragma unroll
    for (int i = 0; i < 32; ++i) {
        const int f = lane + (i << 6);
        const float2 zf = Z[SIG(f)];
        const float2 zm = Z[SIG((LN - f) & (LN - 1))];
        const float Qr = 0.5f * (zf.x + zm.x);
        const float Qi = 0.5f * (zf.y - zm.y);
        const float Kr = 0.5f * (zf.y + zm.y);
        const float Ki = -0.5f * (zf.x - zm.x);
        sx[i] = Qr * Kr + Qi * Ki;
        sy[i] = Qi * Kr - Qr * Ki;
    }
    __syncthreads();
    #pragma unroll
    for (int i = 0; i < 32; ++i) {
        const int f = lane + (i << 6);
        Z[SIG(f)] = make_float2(sx[i], sy[i]);
    }
    __syncthreads();
    #pragma unroll
    for (int i = 0; i < 8; ++i) {
        const int f  = t + (i << 8);
        if (f <= 1024) {
            const int sf = SIG(f);
            const float rx = zb[0][sf].x + zb[1][sf].x + zb[2][sf].x + zb[3][sf].x;
            const float ry = zb[0][sf].y + zb[1][sf].y + zb[2][sf].y + zb[3][sf].y;
            atomicAdd(&spec[((size_t)b * LN + f) * 2 + 0], rx);
            atomicAdd(&spec[((size_t)b * LN + f) * 2 + 1], ry);
        }
    }
}

// ---------------------------------------------------------------------------
// Kernel B: per-b inverse transform -> mean corr, top-7 + softmax.
// Spectrum stored Hermitian-half: reflect for f > 1024.
// ---------------------------------------------------------------------------
__device__ __forceinline__ unsigned bitrev11(unsigned x) {
    return __brev(x) >> (32 - LOG2L);
}

__global__ __launch_bounds__(256) void icorr_topk_kernel(
    const float* __restrict__ spec, float* __restrict__ wts, int* __restrict__ tao) {
    __shared__ float2 zbuf[LN];
    __shared__ float2 tw[LN / 2];
    __shared__ float  cr[LN];
    __shared__ float  rv[256];
    __shared__ int    ri[256];
    __shared__ float  topv[KTOP];
    __shared__ int    topi[KTOP];
    const int tid = threadIdx.x;
    const int b   = blockIdx.x;
    for (int p = tid; p < LN / 2; p += 256) {
        float s, c;
        sincosf(-TWO_PI * (float)p / (float)LN, &s, &c);
        tw[p] = make_float2(c, s);
    }
    for (int f = tid; f < LN; f += 256) {
        const int  fs  = (f <= 1024) ? f : (LN - f);
        const float sg = (f <= 1024) ? -1.f : 1.f;   // zbuf = conj(S[f])
        float sr = spec[((size_t)b * LN + fs) * 2 + 0];
        float si = spec[((size_t)b * LN + fs) * 2 + 1];
        zbuf[bitrev11((unsigned)f)] = make_float2(sr, sg * si);
    }
    __syncthreads();
    for (int s = 0; s < LOG2L; ++s) {
        const int half = 1 << s;
        for (int j = tid; j < LN / 2; j += 256) {
            const int grp = j >> s;
            const int pos = j & (half - 1);
            const int i0  = (grp << (s + 1)) + pos;
            const int i1  = i0 + half;
            const float2 w = tw[pos << (LOG2L - 1 - s)];
            float2 a  = zbuf[i0];
            float2 bv = zbuf[i1];
            float tr = w.x * bv.x - w.y * bv.y;
            float ti = w.x * bv.y + w.y * bv.x;
            zbuf[i0] = make_float2(a.x + tr, a.y + ti);
            zbuf[i1] = make_float2(a.x - tr, a.y - ti);
        }
        __syncthreads();
    }
    const float scale = 1.0f / ((float)LN * (float)HE);
    for (int t = tid; t < LN; t += 256) cr[t] = zbuf[t].x * scale;
    __syncthreads();
    for (int it = 0; it < KTOP; ++it) {
        float mv = -INFINITY;
        int   mi = 0;
        for (int t = tid; t < LN; t += 256) {
            float v = cr[t];
            if (v > mv) { mv = v; mi = t; }
        }
        rv[tid] = mv; ri[tid] = mi;
        __syncthreads();
        for (int off = 128; off > 0; off >>= 1) {
            if (tid < off) {
                float ov = rv[tid + off]; int oi = ri[tid + off];
                if (ov > rv[tid] || (ov == rv[tid] && oi < ri[tid])) {
                    rv[tid] = ov; ri[tid] = oi;
                }
            }
            __syncthreads();
        }
        if (tid == 0) {
            topv[it] = rv[0];
            topi[it] = ri[0];
            cr[ri[0]] = -INFINITY;
        }
        __syncthreads();
    }
    if (tid == 0) {
        float m = topv[0];
        float s = 0.f;
        float ex[KTOP];
        for (int j = 0; j < KTOP; ++j) { ex[j] = __expf(topv[j] - m); s += ex[j]; }
        float inv = 1.0f / s;
        for (int j = 0; j < KTOP; ++j) {
            wts[b * 8 + j] = ex[j] * inv;
            tao[b * 8 + j] = topi[j];
        }
    }
}

// ---------------------------------------------------------------------------
// Kernel C: out[b,l,:,:] = sum_j w[b,j] * V[b,(l+tao_j)%L,:,:]
// wts/tao read directly (uniform addresses, cached) — no LDS, no barrier.
// ---------------------------------------------------------------------------
__global__ __launch_bounds__(256) void gather_kernel(
    const float* __restrict__ v, const float* __restrict__ wts,
    const int* __restrict__ tao, float* __restrict__ out) {
    const int tid = threadIdx.x;
    const int bid = blockIdx.x;
    const int wg  = ((bid & 7) << 11) | (bid >> 3);
    const long long idx = (long long)wg * 256 + tid;
    const int c4 = (int)(idx & 127);
    const int l  = (int)((idx >> 7) & (LN - 1));
    const int b  = (int)(idx >> 18);
    const float4* v4 = (const float4*)v;
    float4 a = make_float4(0.f, 0.f, 0.f, 0.f);
    #pragma unroll
    for (int j = 0; j < KTOP; ++j) {
        const float w  = wts[b * 8 + j];
        const int   dt = tao[b * 8 + j];
        const int   ls = (l + dt) & (LN - 1);
        const float4 x = v4[((size_t)b * LN + ls) * 128 + c4];
        a.x += w * x.x; a.y += w * x.y; a.z += w * x.z; a.w += w * x.w;
    }
    ((float4*)out)[idx] = a;
}

// ---------------------------------------------------------------------------
extern "C" void kernel_launch(void* const* d_in, const int* in_sizes, int n_in,
                              void* d_out, int out_size, void* d_ws, size_t ws_size,
                              hipStream_t stream) {
    const float* q = (const float*)d_in[0];
    const float* k = (const float*)d_in[1];
    const float* v = (const float*)d_in[2];
    float* out = (float*)d_out;

    const size_t nC   = (size_t)BB * HE * LN;          // complex count, 16.7M
    const size_t need = nC * 4 + (size_t)BB * LN * 2 * 4 + (size_t)BB * 8 * 8;

    if (ws_size >= need) {
        unsigned* z    = (unsigned*)d_ws;              // bf16-packed z: 64 MB
        float*    spec = (float*)(z + nC);
        float*    wts  = spec + (size_t)BB * LN * 2;
        int*      tao  = (int*)(wts + BB * 8);

        transpose_pack_kernel<<<BB * 32 * 8, 256, 0, stream>>>(q, k, z, spec);
        fft_reg0_kernel<<<BB * (HE / 4), 256, 0, stream>>>(z, spec);
        icorr_topk_kernel<<<BB, 256, 0, stream>>>(spec, wts, tao);
        const int n4 = BB * LN * HE / 4;
        gather_kernel<<<n4 / 256, 256, 0, stream>>>(v, wts, tao, out);
    } else {
        float* spec = (float*)d_ws;
        float* wts  = spec + (size_t)BB * LN * 2;
        int*   tao  = (int*)(wts + BB * 8);
        hipMemsetAsync(spec, 0, (size_t)BB * LN * 2 * sizeof(float), stream);
        fft_fused_kernel<<<BB * (HE / 4), 256, 0, stream>>>(q, k, spec);
        icorr_topk_kernel<<<BB, 256, 0, stream>>>(spec, wts, tao);
        const int n4 = BB * LN * HE / 4;
        gather_kernel<<<n4 / 256, 256, 0, stream>>>(v, wts, tao, out);
    }
}